// Round 12
// baseline (157.805 us; speedup 1.0000x reference)
//
#include <hip/hip_runtime.h>

typedef short short8 __attribute__((ext_vector_type(8)));
typedef float f32x16 __attribute__((ext_vector_type(16)));
typedef unsigned short ushort_t;

#define B_    16
#define C_    256
#define N_    4096
#define H_    4
#define HID_  128
#define SCALE_ 0.17677669529663687f  /* 32^-0.5 */
#define EPS_  1e-5f

// Native RNE f32->bf16 pair conversion (no gfx950 builtin; RNE == int-emulated f2bf)
__device__ inline unsigned cvtpk(float a, float b) {
  unsigned r;
  asm("v_cvt_pk_bf16_f32 %0, %1, %2" : "=v"(r) : "v"(a), "v"(b));
  return r;
}

__device__ inline int2 pack4(float a, float b, float c, float d) {
  int2 o;
  o.x = (int)cvtpk(a, b);
  o.y = (int)cvtpk(c, d);
  return o;
}

__device__ inline short8 ld_frag16(const ushort_t* p) {  // 16B-aligned
  return __builtin_bit_cast(short8, *(const int4*)p);
}
__device__ inline short8 ld_frag8(const ushort_t* p) {   // 8B-aligned
  int2 a = *(const int2*)p, b = *(const int2*)(p + 4);
  int4 t; t.x = a.x; t.y = a.y; t.z = b.x; t.w = b.y;
  return __builtin_bit_cast(short8, t);
}

// K0: swizzled bf16 W_qkv in MFMA A-fragment order:
//   wsw[((mt*16 + kc)*64 + lane)*8 + j] = W[mt*32 + (lane&31)][kc*16 + (lane>>5)*8 + j]
__global__ void k0_wswz(const float* __restrict__ w, ushort_t* __restrict__ wsw) {
  int gid = blockIdx.x * 256 + threadIdx.x;   // 12288
  int ln = gid & 63, kc = (gid >> 6) & 15, mt = gid >> 10;
  int row = mt * 32 + (ln & 31);
  int col = kc * 16 + (ln >> 5) * 8;
  const float* src = w + (size_t)row * 256 + col;
  float4 a = *(const float4*)src, b = *(const float4*)(src + 4);
  int4 o;
  o.x = (int)cvtpk(a.x, a.y); o.y = (int)cvtpk(a.z, a.w);
  o.z = (int)cvtpk(b.x, b.y); o.w = (int)cvtpk(b.z, b.w);
  *(int4*)(wsw + (size_t)gid * 8) = o;
}

// K1: R6/R11 structure: 256 threads, 4 waves, wave = head.
// ONLY change vs R11: depth-2 prefetch of the 3 W A-frags in the GEMM loop
// (VGPR_Count=48 showed the compiler kept zero cross-iteration pipelining;
// +12 VGPRs fits the (256,3) budget: 96 AGPR + ~60 VGPR < 168).
__global__ __launch_bounds__(256, 3) void k1_qkv(
    const float* __restrict__ x, const ushort_t* __restrict__ wsw,
    ushort_t* __restrict__ qp, float* __restrict__ pctx, float* __restrict__ psum)
{
  __shared__ __align__(16) union {
    ushort_t Xs[64 * 264];                                   // 33 KiB
    struct { ushort_t kt[128 * 68]; ushort_t vt[128 * 68]; } s2;  // 34 KiB
  } sm;

  const int tid = threadIdx.x;
  const int b = blockIdx.y;
  const int blk = blockIdx.x;
  const int n0 = blk * 64;
  const int hw = tid >> 6, lane = tid & 63;   // wave id == head
  const int half = lane >> 5, lm = lane & 31;

  // ---- stage X tile transposed + swizzled: 2 chunks of {8 loads, 8 writes} ----
  {
    const float* xsrc = x + (size_t)b * C_ * N_ + n0;
    const int n4 = tid & 15;
    const int cq0 = tid >> 4;        // 0..15

#define ST_LD(cq, A0, A1, A2, A3) { \
      const float* p_ = xsrc + (size_t)((cq) * 4) * N_ + n4 * 4; \
      A0 = *(const float4*)(p_); \
      A1 = *(const float4*)(p_ + N_); \
      A2 = *(const float4*)(p_ + 2 * N_); \
      A3 = *(const float4*)(p_ + 3 * N_); }

#define ST_WR(cq, A0, A1, A2, A3) { \
      ushort_t* d_ = sm.Xs + ((((cq) >> 1) ^ n4) * 8 + ((cq) & 1) * 4) + (n4 * 4) * 264; \
      *(int2*)(d_ + 0 * 264) = pack4(A0.x, A1.x, A2.x, A3.x); \
      *(int2*)(d_ + 1 * 264) = pack4(A0.y, A1.y, A2.y, A3.y); \
      *(int2*)(d_ + 2 * 264) = pack4(A0.z, A1.z, A2.z, A3.z); \
      *(int2*)(d_ + 3 * 264) = pack4(A0.w, A1.w, A2.w, A3.w); }

    {
      float4 a0, a1, a2, a3, b0, b1, b2, b3;
      ST_LD(cq0,      a0, a1, a2, a3);
      ST_LD(cq0 + 16, b0, b1, b2, b3);
      ST_WR(cq0,      a0, a1, a2, a3);
      ST_WR(cq0 + 16, b0, b1, b2, b3);
    }
    {
      float4 a0, a1, a2, a3, b0, b1, b2, b3;
      ST_LD(cq0 + 32, a0, a1, a2, a3);
      ST_LD(cq0 + 48, b0, b1, b2, b3);
      ST_WR(cq0 + 32, a0, a1, a2, a3);
      ST_WR(cq0 + 48, b0, b1, b2, b3);
    }
#undef ST_LD
#undef ST_WR
  }
  __syncthreads();

  // ---- GEMM: 3 row-tiles (q,k,v of this head) x 2 col-tiles, 16 K-chunks,
  //      depth-2 prefetch of the W A-frags ----
  f32x16 acc0a, acc0b, acc1a, acc1b, acc2a, acc2b;
  for (int r = 0; r < 16; ++r) {
    acc0a[r] = 0.0f; acc0b[r] = 0.0f; acc1a[r] = 0.0f;
    acc1b[r] = 0.0f; acc2a[r] = 0.0f; acc2b[r] = 0.0f;
  }
  {
    const ushort_t* xrow0 = sm.Xs + lm * 264;
    const ushort_t* xrow1 = sm.Xs + (32 + lm) * 264;
    const int sn0 = lm >> 2;          // (n>>2) for col lm
    const int sn1 = 8 + (lm >> 2);    // (n>>2) for col 32+lm
    const ushort_t* wl = wsw + (size_t)(hw * 16 * 64 + lane) * 8;
    // offsets in shorts: +kc*512 per K-chunk, +32768 per mt-group of 4
    short8 nf0 = ld_frag16(wl);
    short8 nf1 = ld_frag16(wl + 32768);
    short8 nf2 = ld_frag16(wl + 65536);
    #pragma unroll
    for (int kc = 0; kc < 16; ++kc) {
      short8 af0 = nf0, af1 = nf1, af2 = nf2;
      if (kc < 15) {
        nf0 = ld_frag16(wl + (kc + 1) * 512);
        nf1 = ld_frag16(wl + 32768 + (kc + 1) * 512);
        nf2 = ld_frag16(wl + 65536 + (kc + 1) * 512);
      }
      short8 b0 = ld_frag16(xrow0 + (((2 * kc + half) ^ sn0) << 3));
      short8 b1 = ld_frag16(xrow1 + (((2 * kc + half) ^ sn1) << 3));
      acc0a = __builtin_amdgcn_mfma_f32_32x32x16_bf16(af0, b0, acc0a, 0, 0, 0);
      acc0b = __builtin_amdgcn_mfma_f32_32x32x16_bf16(af0, b1, acc0b, 0, 0, 0);
      acc1a = __builtin_amdgcn_mfma_f32_32x32x16_bf16(af1, b0, acc1a, 0, 0, 0);
      acc1b = __builtin_amdgcn_mfma_f32_32x32x16_bf16(af1, b1, acc1b, 0, 0, 0);
      acc2a = __builtin_amdgcn_mfma_f32_32x32x16_bf16(af2, b0, acc2a, 0, 0, 0);
      acc2b = __builtin_amdgcn_mfma_f32_32x32x16_bf16(af2, b1, acc2b, 0, 0, 0);
    }
  }

  // ---- q: softmax over d per col, direct global store (k3 B-frag order) ----
  {
    ushort_t* qpb = qp + (size_t)b * N_ * 128;
    // tile a: cols n0+lm, gnt = blk*2
    {
      float m = -1e30f;
      for (int r = 0; r < 16; ++r) m = fmaxf(m, acc0a[r]);
      m = fmaxf(m, __shfl_xor(m, 32));
      float qe[16]; float s = 0.0f;
      for (int r = 0; r < 16; ++r) { qe[r] = __expf(acc0a[r] - m); s += qe[r]; }
      s += __shfl_xor(s, 32);
      float sc = SCALE_ / s;
      const int gnt = blk * 2;
      for (int q = 0; q < 4; ++q) {
        int kc = hw * 2 + (q >> 1);
        int fl = (q & 1) * 32 + lm;
        int2 o = pack4(qe[q * 4 + 0] * sc, qe[q * 4 + 1] * sc,
                       qe[q * 4 + 2] * sc, qe[q * 4 + 3] * sc);
        *(int2*)(qpb + (size_t)((gnt * 8 + kc) * 64 + fl) * 8 + 4 * half) = o;
      }
    }
    // tile b: cols n0+32+lm, gnt = blk*2+1
    {
      float m = -1e30f;
      for (int r = 0; r < 16; ++r) m = fmaxf(m, acc0b[r]);
      m = fmaxf(m, __shfl_xor(m, 32));
      float qe[16]; float s = 0.0f;
      for (int r = 0; r < 16; ++r) { qe[r] = __expf(acc0b[r] - m); s += qe[r]; }
      s += __shfl_xor(s, 32);
      float sc = SCALE_ / s;
      const int gnt = blk * 2 + 1;
      for (int q = 0; q < 4; ++q) {
        int kc = hw * 2 + (q >> 1);
        int fl = (q & 1) * 32 + lm;
        int2 o = pack4(qe[q * 4 + 0] * sc, qe[q * 4 + 1] * sc,
                       qe[q * 4 + 2] * sc, qe[q * 4 + 3] * sc);
        *(int2*)(qpb + (size_t)((gnt * 8 + kc) * 64 + fl) * 8 + 4 * half) = o;
      }
    }
  }

  __syncthreads();   // all waves done reading Xs; s2 live

  // ---- exp(k), v -> LDS kt/vt (d-major, pitch 68); wave owns its 32 rows ----
  for (int r = 0; r < 16; ++r) {
    int row = (r & 3) + 8 * (r >> 2) + 4 * half;
    ushort_t* krow = sm.s2.kt + (hw * 32 + row) * 68;
    ushort_t* vrow = sm.s2.vt + (hw * 32 + row) * 68;
    unsigned kk = cvtpk(__expf(acc1a[r]), __expf(acc1b[r]));
    unsigned vv = cvtpk(acc2a[r], acc2b[r]);
    krow[lm]      = (ushort_t)kk;
    krow[32 + lm] = (ushort_t)(kk >> 16);
    vrow[lm]      = (ushort_t)vv;
    vrow[32 + lm] = (ushort_t)(vv >> 16);
  }
  __syncthreads();

  // ---- ctx + psum partials (each wave its head, full 64 cols):
  // ctx[d][e] = sum_n expk[d,n]*v[e,n];  psum[d] = sum_n expk[d,n] (ones-MFMA).
  {
    f32x16 cacc, sacc;
    for (int r = 0; r < 16; ++r) { cacc[r] = 0.0f; sacc[r] = 0.0f; }
    short8 ones;
    #pragma unroll
    for (int j = 0; j < 8; ++j) ones[j] = (short)0x3F80;  // bf16 1.0
    const ushort_t* ka = sm.s2.kt + (hw * 32 + lm) * 68 + half * 8;
    const ushort_t* va = sm.s2.vt + (hw * 32 + lm) * 68 + half * 8;
    #pragma unroll
    for (int ks = 0; ks < 4; ++ks) {
      short8 af = ld_frag8(ka + ks * 16);
      short8 bf = ld_frag8(va + ks * 16);
      cacc = __builtin_amdgcn_mfma_f32_32x32x16_bf16(af, bf, cacc, 0, 0, 0);
      sacc = __builtin_amdgcn_mfma_f32_32x32x16_bf16(af, ones, sacc, 0, 0, 0);
    }
    float* pc = pctx + ((size_t)(b * 4 + hw) * 64 + blk) * 1024;
    for (int r = 0; r < 16; ++r) {
      int row = (r & 3) + 8 * (r >> 2) + 4 * half;
      pc[row * 32 + lm] = cacc[r];
    }
    if (lm == 0) {   // sacc col-independent; lanes 0 & 32 cover all 32 rows
      float* ps = psum + ((size_t)(b * 4 + hw) * 64 + blk) * 32;
      for (int r = 0; r < 16; ++r) {
        int row = (r & 3) + 8 * (r >> 2) + 4 * half;
        ps[row] = sacc[r];
      }
    }
  }
}

// KRW: fused tree-reduce (pctx 16MB -> LDS, psum 512KB -> LDS) + normalize +
// pre-contract with w_out, write weff in k3 A-frag swizzled order.
__global__ __launch_bounds__(256) void krw(
    const float* __restrict__ pctx, const float* __restrict__ psum,
    const float* __restrict__ wout, ushort_t* __restrict__ weff)
{
  __shared__ float ctxs[32][32];
  __shared__ float inv[32];
  __shared__ float red[8][32];
  const int tid = threadIdx.x;
  const int bh = blockIdx.x;
  const int pb = bh >> 2, ph = bh & 3;

  {
    const int d = tid & 31, part = tid >> 5;
    const float* ps = psum + (size_t)bh * 2048 + part * 8 * 32 + d;
    float t = 0.0f;
    #pragma unroll
    for (int g = 0; g < 8; ++g) t += ps[g * 32];
    red[part][d] = t;
  }
  float4 s4 = make_float4(0.f, 0.f, 0.f, 0.f);
  {
    const float* pc = pctx + (size_t)bh * 65536 + tid * 4;
    #pragma unroll 8
    for (int c = 0; c < 64; ++c) {
      float4 v = *(const float4*)(pc + c * 1024);
      s4.x += v.x; s4.y += v.y; s4.z += v.z; s4.w += v.w;
    }
  }
  __syncthreads();
  if (tid < 32) {
    float u = 0.0f;
    #pragma unroll
    for (int p = 0; p < 8; ++p) u += red[p][tid];
    inv[tid] = 1.0f / (u * 4096.0f);
  }
  __syncthreads();
  {
    float iv = inv[tid >> 3];
    float* crow = &ctxs[0][0] + tid * 4;
    crow[0] = s4.x * iv; crow[1] = s4.y * iv; crow[2] = s4.z * iv; crow[3] = s4.w * iv;
  }
  __syncthreads();
  {
    const int oc = tid;
    const int mt = oc >> 5, lmm = oc & 31;
    const float* wrow = wout + (size_t)oc * HID_ + ph * 32;
    float wr[32];
    for (int e = 0; e < 32; ++e) wr[e] = wrow[e];
    float vals[32];
    for (int d = 0; d < 32; ++d) {
      float s = 0.0f;
      for (int e = 0; e < 32; ++e) s += wr[e] * ctxs[d][e];
      vals[d] = s;
    }
    ushort_t* wb_b = weff + (size_t)pb * 32768;
    for (int kci = 0; kci < 2; ++kci) {
      int kc = ph * 2 + kci;
      for (int hf = 0; hf < 2; ++hf) {
        int d0 = kci * 16 + hf * 8;
        int4 o;
        o.x = (int)cvtpk(vals[d0 + 0], vals[d0 + 1]);
        o.y = (int)cvtpk(vals[d0 + 2], vals[d0 + 3]);
        o.z = (int)cvtpk(vals[d0 + 4], vals[d0 + 5]);
        o.w = (int)cvtpk(vals[d0 + 6], vals[d0 + 7]);
        *(int4*)(wb_b + (size_t)((mt * 8 + kc) * 64 + hf * 32 + lmm) * 8) = o;
      }
    }
  }
}

// K3: out = W_eff_b @ q'^T + b_out, LayerNorm per column, fp32 store.
__global__ __launch_bounds__(256, 4) void k3_out(
    const ushort_t* __restrict__ weff, const ushort_t* __restrict__ qp,
    const float* __restrict__ bout, const float* __restrict__ g,
    float* __restrict__ out)
{
  __shared__ float part_s[2][64], part_s2[2][64];
  __shared__ float st_mu[64], st_rs[64];

  const int tid = threadIdx.x;
  const int b = blockIdx.y;
  const int blk = blockIdx.x;
  const int n0 = blk * 64;
  const int w = tid >> 6, lane = tid & 63;
  const int half = lane >> 5, lm = lane & 31;
  const int ntile = w & 1, mgrp = w >> 1;
  const int gnt = blk * 2 + ntile;

  f32x16 acc[4];
  for (int i = 0; i < 4; ++i)
    for (int r = 0; r < 16; ++r) acc[i][r] = 0.0f;

  {
    const ushort_t* qb = qp + (size_t)b * N_ * 128 + (size_t)gnt * 8 * 64 * 8;
    const ushort_t* wbase = weff + (size_t)b * 32768 + ((size_t)(mgrp * 4) * 8 * 64 + lane) * 8;
    for (int kc = 0; kc < 8; ++kc) {
      short8 bfrag = ld_frag16(qb + (size_t)(kc * 64 + lane) * 8);
      for (int i = 0; i < 4; ++i) {
        short8 af = ld_frag16(wbase + (size_t)((i * 8 + kc) * 64) * 8);
        acc[i] = __builtin_amdgcn_mfma_f32_32x32x16_bf16(af, bfrag, acc[i], 0, 0, 0);
      }
    }
  }

  float s = 0.0f, s2v = 0.0f;
  for (int i = 0; i < 4; ++i) {
    int mt = mgrp * 4 + i;
    for (int r = 0; r < 16; ++r) {
      int row = mt * 32 + (r & 3) + 8 * (r >> 2) + 4 * half;
      acc[i][r] += bout[row];
      float v = acc[i][r];
      s += v; s2v += v * v;
    }
  }
  s += __shfl_xor(s, 32);
  s2v += __shfl_xor(s2v, 32);
  if (half == 0) { part_s[mgrp][ntile * 32 + lm] = s; part_s2[mgrp][ntile * 32 + lm] = s2v; }
  __syncthreads();
  if (tid < 64) {
    float S = part_s[0][tid] + part_s[1][tid];
    float S2 = part_s2[0][tid] + part_s2[1][tid];
    float mu = S * (1.0f / 256.0f);
    float var = S2 * (1.0f / 256.0f) - mu * mu;
    st_mu[tid] = mu;
    st_rs[tid] = rsqrtf(var + EPS_);
  }
  __syncthreads();

  const int col = ntile * 32 + lm;
  const float mu = st_mu[col];
  const float rs = st_rs[col];
  float* ob = out + (size_t)b * C_ * N_ + n0 + col;
  for (int i = 0; i < 4; ++i) {
    int mt = mgrp * 4 + i;
    for (int r = 0; r < 16; ++r) {
      int row = mt * 32 + (r & 3) + 8 * (r >> 2) + 4 * half;
      ob[(size_t)row * N_] = (acc[i][r] - mu) * rs * g[row];
    }
  }
}

extern "C" void kernel_launch(void* const* d_in, const int* in_sizes, int n_in,
                              void* d_out, int out_size, void* d_ws, size_t ws_size,
                              hipStream_t stream) {
  (void)in_sizes; (void)n_in; (void)out_size; (void)ws_size;
  const float* x    = (const float*)d_in[0];
  const float* wqkv = (const float*)d_in[1];
  const float* wout = (const float*)d_in[2];
  const float* bout = (const float*)d_in[3];
  const float* g    = (const float*)d_in[4];
  float* out = (float*)d_out;

  char* ws = (char*)d_ws;
  ushort_t* qp    = (ushort_t*)(ws);                      // 16 MiB swizzled q' bf16
  float*    pctx  = (float*)(ws + ((size_t)16 << 20));    // 16 MiB (b,h,64blk,32,32) fp32
  float*    psum  = (float*)(ws + ((size_t)32 << 20));    // 512 KiB (b,h,64blk,32) fp32
  ushort_t* weff  = (ushort_t*)(ws + ((size_t)32 << 20) + (512 << 10)); // 1 MiB swizzled
  ushort_t* wsw   = (ushort_t*)(ws + ((size_t)33 << 20) + (512 << 10)); // 192 KiB swizzled W_qkv

  k0_wswz<<<48, 256, 0, stream>>>(wqkv, wsw);
  k1_qkv<<<dim3(64, 16), 256, 0, stream>>>(x, wsw, qp, pctx, psum);
  krw<<<64, 256, 0, stream>>>(pctx, psum, wout, weff);
  k3_out<<<dim3(64, 16), 256, 0, stream>>>(weff, qp, bout, g, out);
}

// Round 13
// 155.794 us; speedup vs baseline: 1.0129x; 1.0129x over previous
//
#include <hip/hip_runtime.h>

typedef short short8 __attribute__((ext_vector_type(8)));
typedef float f32x16 __attribute__((ext_vector_type(16)));
typedef unsigned short ushort_t;

#define B_    16
#define C_    256
#define N_    4096
#define H_    4
#define HID_  128
#define SCALE_ 0.17677669529663687f  /* 32^-0.5 */
#define EPS_  1e-5f

// Native RNE f32->bf16 pair conversion (no gfx950 builtin; RNE == int-emulated f2bf)
__device__ inline unsigned cvtpk(float a, float b) {
  unsigned r;
  asm("v_cvt_pk_bf16_f32 %0, %1, %2" : "=v"(r) : "v"(a), "v"(b));
  return r;
}

__device__ inline int2 pack4(float a, float b, float c, float d) {
  int2 o;
  o.x = (int)cvtpk(a, b);
  o.y = (int)cvtpk(c, d);
  return o;
}

__device__ inline short8 ld_frag16(const ushort_t* p) {  // 16B-aligned
  return __builtin_bit_cast(short8, *(const int4*)p);
}
__device__ inline short8 ld_frag8(const ushort_t* p) {   // 8B-aligned
  int2 a = *(const int2*)p, b = *(const int2*)(p + 4);
  int4 t; t.x = a.x; t.y = a.y; t.z = b.x; t.w = b.y;
  return __builtin_bit_cast(short8, t);
}

// K0: swizzled bf16 W_qkv in MFMA A-fragment order:
//   wsw[((mt*16 + kc)*64 + lane)*8 + j] = W[mt*32 + (lane&31)][kc*16 + (lane>>5)*8 + j]
__global__ void k0_wswz(const float* __restrict__ w, ushort_t* __restrict__ wsw) {
  int gid = blockIdx.x * 256 + threadIdx.x;   // 12288
  int ln = gid & 63, kc = (gid >> 6) & 15, mt = gid >> 10;
  int row = mt * 32 + (ln & 31);
  int col = kc * 16 + (ln >> 5) * 8;
  const float* src = w + (size_t)row * 256 + col;
  float4 a = *(const float4*)src, b = *(const float4*)(src + 4);
  int4 o;
  o.x = (int)cvtpk(a.x, a.y); o.y = (int)cvtpk(a.z, a.w);
  o.z = (int)cvtpk(b.x, b.y); o.w = (int)cvtpk(b.z, b.w);
  *(int4*)(wsw + (size_t)gid * 8) = o;
}

// K1: best-measured structure (R6, 155.8 us): 256 threads, 4 waves, wave = head,
// covering ALL 64 n-cols; per kc 3 A-frags + 2 B-frags -> 6 MFMAs per A-load.
// Xs layout [n][c] pitch 264 with XOR-swizzled 16B blocks.
// launch_bounds(256,3): (256,4) spills (R7); reorders spill (R8); W-prefetch
// drops occupancy (R12) — this configuration is the measured optimum.
__global__ __launch_bounds__(256, 3) void k1_qkv(
    const float* __restrict__ x, const ushort_t* __restrict__ wsw,
    ushort_t* __restrict__ qp, float* __restrict__ pctx, float* __restrict__ psum)
{
  __shared__ __align__(16) union {
    ushort_t Xs[64 * 264];                                   // 33 KiB
    struct { ushort_t kt[128 * 68]; ushort_t vt[128 * 68]; } s2;  // 34 KiB
  } sm;

  const int tid = threadIdx.x;
  const int b = blockIdx.y;
  const int blk = blockIdx.x;
  const int n0 = blk * 64;
  const int hw = tid >> 6, lane = tid & 63;   // wave id == head
  const int half = lane >> 5, lm = lane & 31;

  // ---- stage X tile transposed + swizzled (16 float4 loads / thread) ----
  {
    const float* xsrc = x + (size_t)b * C_ * N_ + n0;
    const int n4 = tid & 15;
    const int cq0 = tid >> 4;        // 0..15
    #pragma unroll
    for (int cc = 0; cc < 4; ++cc) {
      const int cq = cq0 + cc * 16;
      const float* p = xsrc + (size_t)(cq * 4) * N_ + n4 * 4;
      float4 a0 = *(const float4*)(p);
      float4 a1 = *(const float4*)(p + N_);
      float4 a2 = *(const float4*)(p + 2 * N_);
      float4 a3 = *(const float4*)(p + 3 * N_);
      ushort_t* d = sm.Xs + (((cq >> 1) ^ n4) * 8 + (cq & 1) * 4) + (n4 * 4) * 264;
      *(int2*)(d + 0 * 264) = pack4(a0.x, a1.x, a2.x, a3.x);
      *(int2*)(d + 1 * 264) = pack4(a0.y, a1.y, a2.y, a3.y);
      *(int2*)(d + 2 * 264) = pack4(a0.z, a1.z, a2.z, a3.z);
      *(int2*)(d + 3 * 264) = pack4(a0.w, a1.w, a2.w, a3.w);
    }
  }
  __syncthreads();

  // ---- GEMM: 3 row-tiles (q,k,v of this head) x 2 col-tiles, 16 K-chunks ----
  f32x16 acc0a, acc0b, acc1a, acc1b, acc2a, acc2b;
  for (int r = 0; r < 16; ++r) {
    acc0a[r] = 0.0f; acc0b[r] = 0.0f; acc1a[r] = 0.0f;
    acc1b[r] = 0.0f; acc2a[r] = 0.0f; acc2b[r] = 0.0f;
  }
  {
    const ushort_t* xrow0 = sm.Xs + lm * 264;
    const ushort_t* xrow1 = sm.Xs + (32 + lm) * 264;
    const int sn0 = lm >> 2;          // (n>>2) for col lm
    const int sn1 = 8 + (lm >> 2);    // (n>>2) for col 32+lm
    const ushort_t* wl = wsw + (size_t)(hw * 16 * 64 + lane) * 8;
    // offsets in shorts: +kc*512 per K-chunk, +32768 per mt-group of 4
    #pragma unroll
    for (int kc = 0; kc < 16; ++kc) {
      short8 b0 = ld_frag16(xrow0 + (((2 * kc + half) ^ sn0) << 3));
      short8 b1 = ld_frag16(xrow1 + (((2 * kc + half) ^ sn1) << 3));
      short8 af0 = ld_frag16(wl + kc * 512);
      short8 af1 = ld_frag16(wl + 32768 + kc * 512);
      short8 af2 = ld_frag16(wl + 65536 + kc * 512);
      acc0a = __builtin_amdgcn_mfma_f32_32x32x16_bf16(af0, b0, acc0a, 0, 0, 0);
      acc0b = __builtin_amdgcn_mfma_f32_32x32x16_bf16(af0, b1, acc0b, 0, 0, 0);
      acc1a = __builtin_amdgcn_mfma_f32_32x32x16_bf16(af1, b0, acc1a, 0, 0, 0);
      acc1b = __builtin_amdgcn_mfma_f32_32x32x16_bf16(af1, b1, acc1b, 0, 0, 0);
      acc2a = __builtin_amdgcn_mfma_f32_32x32x16_bf16(af2, b0, acc2a, 0, 0, 0);
      acc2b = __builtin_amdgcn_mfma_f32_32x32x16_bf16(af2, b1, acc2b, 0, 0, 0);
    }
  }

  // ---- q: softmax over d per col, direct global store (k3 B-frag order) ----
  {
    ushort_t* qpb = qp + (size_t)b * N_ * 128;
    // tile a: cols n0+lm, gnt = blk*2
    {
      float m = -1e30f;
      for (int r = 0; r < 16; ++r) m = fmaxf(m, acc0a[r]);
      m = fmaxf(m, __shfl_xor(m, 32));
      float qe[16]; float s = 0.0f;
      for (int r = 0; r < 16; ++r) { qe[r] = __expf(acc0a[r] - m); s += qe[r]; }
      s += __shfl_xor(s, 32);
      float sc = SCALE_ / s;
      const int gnt = blk * 2;
      for (int q = 0; q < 4; ++q) {
        int kc = hw * 2 + (q >> 1);
        int fl = (q & 1) * 32 + lm;
        int2 o = pack4(qe[q * 4 + 0] * sc, qe[q * 4 + 1] * sc,
                       qe[q * 4 + 2] * sc, qe[q * 4 + 3] * sc);
        *(int2*)(qpb + (size_t)((gnt * 8 + kc) * 64 + fl) * 8 + 4 * half) = o;
      }
    }
    // tile b: cols n0+32+lm, gnt = blk*2+1
    {
      float m = -1e30f;
      for (int r = 0; r < 16; ++r) m = fmaxf(m, acc0b[r]);
      m = fmaxf(m, __shfl_xor(m, 32));
      float qe[16]; float s = 0.0f;
      for (int r = 0; r < 16; ++r) { qe[r] = __expf(acc0b[r] - m); s += qe[r]; }
      s += __shfl_xor(s, 32);
      float sc = SCALE_ / s;
      const int gnt = blk * 2 + 1;
      for (int q = 0; q < 4; ++q) {
        int kc = hw * 2 + (q >> 1);
        int fl = (q & 1) * 32 + lm;
        int2 o = pack4(qe[q * 4 + 0] * sc, qe[q * 4 + 1] * sc,
                       qe[q * 4 + 2] * sc, qe[q * 4 + 3] * sc);
        *(int2*)(qpb + (size_t)((gnt * 8 + kc) * 64 + fl) * 8 + 4 * half) = o;
      }
    }
  }

  __syncthreads();   // all waves done reading Xs; s2 live

  // ---- exp(k), v -> LDS kt/vt (d-major, pitch 68); wave owns its 32 rows ----
  for (int r = 0; r < 16; ++r) {
    int row = (r & 3) + 8 * (r >> 2) + 4 * half;
    ushort_t* krow = sm.s2.kt + (hw * 32 + row) * 68;
    ushort_t* vrow = sm.s2.vt + (hw * 32 + row) * 68;
    unsigned kk = cvtpk(__expf(acc1a[r]), __expf(acc1b[r]));
    unsigned vv = cvtpk(acc2a[r], acc2b[r]);
    krow[lm]      = (ushort_t)kk;
    krow[32 + lm] = (ushort_t)(kk >> 16);
    vrow[lm]      = (ushort_t)vv;
    vrow[32 + lm] = (ushort_t)(vv >> 16);
  }
  __syncthreads();

  // ---- ctx + psum partials (each wave its head, full 64 cols):
  // ctx[d][e] = sum_n expk[d,n]*v[e,n];  psum[d] = sum_n expk[d,n] (ones-MFMA).
  {
    f32x16 cacc, sacc;
    for (int r = 0; r < 16; ++r) { cacc[r] = 0.0f; sacc[r] = 0.0f; }
    short8 ones;
    #pragma unroll
    for (int j = 0; j < 8; ++j) ones[j] = (short)0x3F80;  // bf16 1.0
    const ushort_t* ka = sm.s2.kt + (hw * 32 + lm) * 68 + half * 8;
    const ushort_t* va = sm.s2.vt + (hw * 32 + lm) * 68 + half * 8;
    #pragma unroll
    for (int ks = 0; ks < 4; ++ks) {
      short8 af = ld_frag8(ka + ks * 16);
      short8 bf = ld_frag8(va + ks * 16);
      cacc = __builtin_amdgcn_mfma_f32_32x32x16_bf16(af, bf, cacc, 0, 0, 0);
      sacc = __builtin_amdgcn_mfma_f32_32x32x16_bf16(af, ones, sacc, 0, 0, 0);
    }
    float* pc = pctx + ((size_t)(b * 4 + hw) * 64 + blk) * 1024;
    for (int r = 0; r < 16; ++r) {
      int row = (r & 3) + 8 * (r >> 2) + 4 * half;
      pc[row * 32 + lm] = cacc[r];
    }
    if (lm == 0) {   // sacc col-independent; lanes 0 & 32 cover all 32 rows
      float* ps = psum + ((size_t)(b * 4 + hw) * 64 + blk) * 32;
      for (int r = 0; r < 16; ++r) {
        int row = (r & 3) + 8 * (r >> 2) + 4 * half;
        ps[row] = sacc[r];
      }
    }
  }
}

// KRW: fused tree-reduce (pctx 16MB -> LDS, psum 512KB -> LDS) + normalize +
// pre-contract with w_out, write weff in k3 A-frag swizzled order.
// (Fused version — R10 proved splitting costs +2.6 us.)
__global__ __launch_bounds__(256) void krw(
    const float* __restrict__ pctx, const float* __restrict__ psum,
    const float* __restrict__ wout, ushort_t* __restrict__ weff)
{
  __shared__ float ctxs[32][32];
  __shared__ float inv[32];
  __shared__ float red[8][32];
  const int tid = threadIdx.x;
  const int bh = blockIdx.x;
  const int pb = bh >> 2, ph = bh & 3;

  {
    const int d = tid & 31, part = tid >> 5;
    const float* ps = psum + (size_t)bh * 2048 + part * 8 * 32 + d;
    float t = 0.0f;
    #pragma unroll
    for (int g = 0; g < 8; ++g) t += ps[g * 32];
    red[part][d] = t;
  }
  float4 s4 = make_float4(0.f, 0.f, 0.f, 0.f);
  {
    const float* pc = pctx + (size_t)bh * 65536 + tid * 4;
    #pragma unroll 8
    for (int c = 0; c < 64; ++c) {
      float4 v = *(const float4*)(pc + c * 1024);
      s4.x += v.x; s4.y += v.y; s4.z += v.z; s4.w += v.w;
    }
  }
  __syncthreads();
  if (tid < 32) {
    float u = 0.0f;
    #pragma unroll
    for (int p = 0; p < 8; ++p) u += red[p][tid];
    inv[tid] = 1.0f / (u * 4096.0f);
  }
  __syncthreads();
  {
    float iv = inv[tid >> 3];
    float* crow = &ctxs[0][0] + tid * 4;
    crow[0] = s4.x * iv; crow[1] = s4.y * iv; crow[2] = s4.z * iv; crow[3] = s4.w * iv;
  }
  __syncthreads();
  {
    const int oc = tid;
    const int mt = oc >> 5, lmm = oc & 31;
    const float* wrow = wout + (size_t)oc * HID_ + ph * 32;
    float wr[32];
    for (int e = 0; e < 32; ++e) wr[e] = wrow[e];
    float vals[32];
    for (int d = 0; d < 32; ++d) {
      float s = 0.0f;
      for (int e = 0; e < 32; ++e) s += wr[e] * ctxs[d][e];
      vals[d] = s;
    }
    ushort_t* wb_b = weff + (size_t)pb * 32768;
    for (int kci = 0; kci < 2; ++kci) {
      int kc = ph * 2 + kci;
      for (int hf = 0; hf < 2; ++hf) {
        int d0 = kci * 16 + hf * 8;
        int4 o;
        o.x = (int)cvtpk(vals[d0 + 0], vals[d0 + 1]);
        o.y = (int)cvtpk(vals[d0 + 2], vals[d0 + 3]);
        o.z = (int)cvtpk(vals[d0 + 4], vals[d0 + 5]);
        o.w = (int)cvtpk(vals[d0 + 6], vals[d0 + 7]);
        *(int4*)(wb_b + (size_t)((mt * 8 + kc) * 64 + hf * 32 + lmm) * 8) = o;
      }
    }
  }
}

// K3: out = W_eff_b @ q'^T + b_out, LayerNorm per column, fp32 store.
// Direct coalesced stores (R9 proved LDS routing hurts).
__global__ __launch_bounds__(256, 4) void k3_out(
    const ushort_t* __restrict__ weff, const ushort_t* __restrict__ qp,
    const float* __restrict__ bout, const float* __restrict__ g,
    float* __restrict__ out)
{
  __shared__ float part_s[2][64], part_s2[2][64];
  __shared__ float st_mu[64], st_rs[64];

  const int tid = threadIdx.x;
  const int b = blockIdx.y;
  const int blk = blockIdx.x;
  const int n0 = blk * 64;
  const int w = tid >> 6, lane = tid & 63;
  const int half = lane >> 5, lm = lane & 31;
  const int ntile = w & 1, mgrp = w >> 1;
  const int gnt = blk * 2 + ntile;

  f32x16 acc[4];
  for (int i = 0; i < 4; ++i)
    for (int r = 0; r < 16; ++r) acc[i][r] = 0.0f;

  {
    const ushort_t* qb = qp + (size_t)b * N_ * 128 + (size_t)gnt * 8 * 64 * 8;
    const ushort_t* wbase = weff + (size_t)b * 32768 + ((size_t)(mgrp * 4) * 8 * 64 + lane) * 8;
    for (int kc = 0; kc < 8; ++kc) {
      short8 bfrag = ld_frag16(qb + (size_t)(kc * 64 + lane) * 8);
      for (int i = 0; i < 4; ++i) {
        short8 af = ld_frag16(wbase + (size_t)((i * 8 + kc) * 64) * 8);
        acc[i] = __builtin_amdgcn_mfma_f32_32x32x16_bf16(af, bfrag, acc[i], 0, 0, 0);
      }
    }
  }

  float s = 0.0f, s2v = 0.0f;
  for (int i = 0; i < 4; ++i) {
    int mt = mgrp * 4 + i;
    for (int r = 0; r < 16; ++r) {
      int row = mt * 32 + (r & 3) + 8 * (r >> 2) + 4 * half;
      acc[i][r] += bout[row];
      float v = acc[i][r];
      s += v; s2v += v * v;
    }
  }
  s += __shfl_xor(s, 32);
  s2v += __shfl_xor(s2v, 32);
  if (half == 0) { part_s[mgrp][ntile * 32 + lm] = s; part_s2[mgrp][ntile * 32 + lm] = s2v; }
  __syncthreads();
  if (tid < 64) {
    float S = part_s[0][tid] + part_s[1][tid];
    float S2 = part_s2[0][tid] + part_s2[1][tid];
    float mu = S * (1.0f / 256.0f);
    float var = S2 * (1.0f / 256.0f) - mu * mu;
    st_mu[tid] = mu;
    st_rs[tid] = rsqrtf(var + EPS_);
  }
  __syncthreads();

  const int col = ntile * 32 + lm;
  const float mu = st_mu[col];
  const float rs = st_rs[col];
  float* ob = out + (size_t)b * C_ * N_ + n0 + col;
  for (int i = 0; i < 4; ++i) {
    int mt = mgrp * 4 + i;
    for (int r = 0; r < 16; ++r) {
      int row = mt * 32 + (r & 3) + 8 * (r >> 2) + 4 * half;
      ob[(size_t)row * N_] = (acc[i][r] - mu) * rs * g[row];
    }
  }
}

extern "C" void kernel_launch(void* const* d_in, const int* in_sizes, int n_in,
                              void* d_out, int out_size, void* d_ws, size_t ws_size,
                              hipStream_t stream) {
  (void)in_sizes; (void)n_in; (void)out_size; (void)ws_size;
  const float* x    = (const float*)d_in[0];
  const float* wqkv = (const float*)d_in[1];
  const float* wout = (const float*)d_in[2];
  const float* bout = (const float*)d_in[3];
  const float* g    = (const float*)d_in[4];
  float* out = (float*)d_out;

  char* ws = (char*)d_ws;
  ushort_t* qp    = (ushort_t*)(ws);                      // 16 MiB swizzled q' bf16
  float*    pctx  = (float*)(ws + ((size_t)16 << 20));    // 16 MiB (b,h,64blk,32,32) fp32
  float*    psum  = (float*)(ws + ((size_t)32 << 20));    // 512 KiB (b,h,64blk,32) fp32
  ushort_t* weff  = (ushort_t*)(ws + ((size_t)32 << 20) + (512 << 10)); // 1 MiB swizzled
  ushort_t* wsw   = (ushort_t*)(ws + ((size_t)33 << 20) + (512 << 10)); // 192 KiB swizzled W_qkv

  k0_wswz<<<48, 256, 0, stream>>>(wqkv, wsw);
  k1_qkv<<<dim3(64, 16), 256, 0, stream>>>(x, wsw, qp, pctx, psum);
  krw<<<64, 256, 0, stream>>>(pctx, psum, wout, weff);
  k3_out<<<dim3(64, 16), 256, 0, stream>>>(weff, qp, bout, g, out);
}